// Round 15
// baseline (399.222 us; speedup 1.0000x reference)
//
#include <hip/hip_runtime.h>
#include <math.h>

#define DIM 96
#define HW_ 9216               // 96*96
#define N3 884736              // 96^3
#define TPB 256
#define EPSF 1e-6f

template<int K> struct CW { float w[K]; };

// Native clang vector type accepted by the nontemporal builtins.
typedef float nfloat4 __attribute__((ext_vector_type(4)));

__device__ inline float4 ld4(const float* p) { return *reinterpret_cast<const float4*>(p); }
__device__ inline float4 nt_ld4(const float* p) {
  nfloat4 v = __builtin_nontemporal_load(reinterpret_cast<const nfloat4*>(p));
  return make_float4(v.x, v.y, v.z, v.w);
}
__device__ inline void nt_st4(float* p, float4 v) {
  nfloat4 n = {v.x, v.y, v.z, v.w};
  __builtin_nontemporal_store(n, reinterpret_cast<nfloat4*>(p));
}
__device__ inline float4 fma4(float w, float4 a, float4 acc) {
  acc.x = fmaf(w, a.x, acc.x); acc.y = fmaf(w, a.y, acc.y);
  acc.z = fmaf(w, a.z, acc.z); acc.w = fmaf(w, a.w, acc.w); return acc;
}
// XCD-aware contiguous-chunk swizzle (grid must be divisible by 8; all ours are).
__device__ inline int xswz(int bid, int nb) { return (bid & 7) * (nb >> 3) + (bid >> 3); }

// K1: dual 7-tap conv along W over nvol volumes, 4 outputs/thread.
__global__ void k1_dualW(const float* __restrict__ p0, const float* __restrict__ p1,
                         const float* __restrict__ p2, const float* __restrict__ p3,
                         float* __restrict__ A, int nvol, CW<7> g, CW<7> dg) {
  int t = blockIdx.x * TPB + threadIdx.x;
  if (t >= nvol * (N3 / 4)) return;
  int base = t * 4;
  int v = base / N3, i = base - v * N3;   // i % 4 == 0
  const float* src = (v == 0) ? p0 : (v == 1) ? p1 : (v == 2) ? p2 : p3;
  int x = i % DIM;
  float win[10];
#pragma unroll
  for (int u = 0; u < 10; ++u) {
    int xx = x + u - 3;
    win[u] = (0 <= xx && xx < DIM) ? src[i + u - 3] : 0.f;
  }
  float4 sa, sb;
#pragma unroll
  for (int k = 0; k < 4; ++k) {
    float a_ = 0.f, b_ = 0.f;
#pragma unroll
    for (int j = 0; j < 7; ++j) {
      float val = win[k + j];
      a_ = fmaf(g.w[j], val, a_);
      b_ = fmaf(dg.w[j], val, b_);
    }
    ((float*)&sa)[k] = a_;
    ((float*)&sb)[k] = b_;
  }
  nt_st4(A + (size_t)(2 * v) * N3 + i, sa);
  nt_st4(A + (size_t)(2 * v + 1) * N3 + i, sb);
}

// K2: 7-tap conv along H (float4). In fields [2v],[2v+1]. Out [3v+t]:
// t0 = Hg(Wg) [->gz], t1 = Hdg(Wg) [->gy], t2 = Hg(Wdg) [->gx]
__global__ void k2_H(const float* __restrict__ A, float* __restrict__ B,
                     int nvol, CW<7> g, CW<7> dg) {
  int t = blockIdx.x * TPB + threadIdx.x;
  if (t >= nvol * (N3 / 4)) return;
  int base = t * 4;
  int v = base / N3, i = base - v * N3;
  int h = (i / DIM) % DIM;
  const float* Wg  = A + (size_t)(2 * v) * N3;
  const float* Wdg = A + (size_t)(2 * v + 1) * N3;
  float4 t0 = {0,0,0,0}, t1 = {0,0,0,0}, t2 = {0,0,0,0};
#pragma unroll
  for (int j = -3; j <= 3; ++j) {
    int hh = h + j;
    if (0 <= hh && hh < DIM) {
      float4 a = ld4(Wg + i + j * DIM);
      t0 = fma4(g.w[j + 3], a, t0);
      t1 = fma4(dg.w[j + 3], a, t1);
      float4 b = ld4(Wdg + i + j * DIM);
      t2 = fma4(g.w[j + 3], b, t2);
    }
  }
  nt_st4(B + (size_t)(3 * v + 0) * N3 + i, t0);
  nt_st4(B + (size_t)(3 * v + 1) * N3 + i, t1);
  nt_st4(B + (size_t)(3 * v + 2) * N3 + i, t2);
}

// K3: 7-tap conv along D (float4) on nf fields; field f%3==0 uses dg, else g.
__global__ void k3_D(const float* __restrict__ B, float* __restrict__ A,
                     int nf, CW<7> g, CW<7> dg) {
  int t = xswz(blockIdx.x, gridDim.x) * TPB + threadIdx.x;
  if (t >= nf * (N3 / 4)) return;
  int base = t * 4;
  int f = base / N3;
  int d = (base / HW_) % DIM;
  bool use_dg = (f % 3 == 0);
  float4 acc = {0,0,0,0};
#pragma unroll
  for (int j = -3; j <= 3; ++j) {
    int dd = d + j;
    if (0 <= dd && dd < DIM) {
      float w = use_dg ? dg.w[j + 3] : g.w[j + 3];
      acc = fma4(w, ld4(B + base + j * HW_), acc);
    }
  }
  nt_st4(A + base, acc);
}

// K4: gradient products + 13-tap blur along W. In fields [3v+t] -> out [6v+c].
// XCD-swizzled; non-temporal stores (outputs not re-read by this pass).
__global__ void k4_prodW(const float* __restrict__ A, float* __restrict__ C,
                         int nvol, CW<13> w13) {
  int t = xswz(blockIdx.x, gridDim.x) * TPB + threadIdx.x;
  if (t >= nvol * (N3 / 4)) return;
  int base = t * 4;
  int v = base / N3, i = base - v * N3;
  const float* gz = A + (size_t)(3 * v + 0) * N3;
  const float* gy = A + (size_t)(3 * v + 1) * N3;
  const float* gx = A + (size_t)(3 * v + 2) * N3;
  int x = i % DIM;
  float wx[16], wy[16], wz[16];
#pragma unroll
  for (int u = 0; u < 16; ++u) {
    int xx = x + u - 6;
    bool ok = (0 <= xx && xx < DIM);
    wx[u] = ok ? gx[i + u - 6] : 0.f;
    wy[u] = ok ? gy[i + u - 6] : 0.f;
    wz[u] = ok ? gz[i + u - 6] : 0.f;
  }
  float4 a0 = {0,0,0,0}, a1 = {0,0,0,0}, a2 = {0,0,0,0};
  float4 a3 = {0,0,0,0}, a4 = {0,0,0,0}, a5 = {0,0,0,0};
#pragma unroll
  for (int k = 0; k < 4; ++k) {
    float s0=0,s1=0,s2=0,s3=0,s4=0,s5=0;
#pragma unroll
    for (int j = 0; j < 13; ++j) {
      float w = w13.w[j];
      float a = wx[k + j], b = wy[k + j], c = wz[k + j];
      float wa = w * a, wb = w * b, wc = w * c;
      s0 = fmaf(wa, a, s0); s3 = fmaf(wa, b, s3); s4 = fmaf(wa, c, s4);
      s1 = fmaf(wb, b, s1); s5 = fmaf(wb, c, s5);
      s2 = fmaf(wc, c, s2);
    }
    ((float*)&a0)[k]=s0; ((float*)&a1)[k]=s1; ((float*)&a2)[k]=s2;
    ((float*)&a3)[k]=s3; ((float*)&a4)[k]=s4; ((float*)&a5)[k]=s5;
  }
  float* dst = C + (size_t)(6 * v) * N3;
  nt_st4(dst + 0*N3 + i, a0); nt_st4(dst + 1*N3 + i, a1); nt_st4(dst + 2*N3 + i, a2);
  nt_st4(dst + 3*N3 + i, a3); nt_st4(dst + 4*N3 + i, a4); nt_st4(dst + 5*N3 + i, a5);
}

// K5: 13-tap blur along axis with compile-time STRIDE (DIM=H, HW_=D) on nf
// fields (float4), In -> Out. XCD-swizzled for slab/L2 reuse.
template<int STRIDE>
__global__ void k5_blur(const float* __restrict__ In, float* __restrict__ Out,
                        int nf, CW<13> w13) {
  int t = xswz(blockIdx.x, gridDim.x) * TPB + threadIdx.x;
  if (t >= nf * (N3 / 4)) return;
  int base = t * 4;
  int c = (base / STRIDE) % DIM;
  float4 acc = {0,0,0,0};
#pragma unroll
  for (int j = -6; j <= 6; ++j) {
    int cc = c + j;
    if (0 <= cc && cc < DIM)
      acc = fma4(w13.w[j + 6], ld4(In + base + j * STRIDE), acc);
  }
  nt_st4(Out + base, acc);
}

// ---- analytic symmetric-3x3 matrix log ----
// Trigonometric eigenvalues (descending l0>=l1>=l2) + Newton divided-difference
// polynomial interpolating y=log(max(lambda,EPS)) at x=lambda:
//   log(M) = c0 I + c1 M + c2 M^2.
__device__ inline void logm3(const float s6[6], float L[6]) {
  const float Sxx=s6[0], Syy=s6[1], Szz=s6[2], Sxy=s6[3], Sxz=s6[4], Syz=s6[5];
  float q  = (Sxx + Syy + Szz) * (1.f/3.f);
  float p1 = Sxy*Sxy + Sxz*Sxz + Syz*Syz;
  float axx = Sxx - q, ayy = Syy - q, azz = Szz - q;
  float p2 = axx*axx + ayy*ayy + azz*azz + 2.f*p1;
  float l0, l1, l2;
  if (p2 < 1e-24f) {
    l0 = l1 = l2 = q;
  } else {
    float p  = sqrtf(p2 * (1.f/6.f));
    float ip = __frcp_rn(p);
    float bxx=axx*ip, byy=ayy*ip, bzz=azz*ip;
    float bxy=Sxy*ip, bxz=Sxz*ip, byz=Syz*ip;
    float detB = bxx*(byy*bzz - byz*byz) - bxy*(bxy*bzz - byz*bxz)
               + bxz*(bxy*byz - byy*bxz);
    float r = fminf(1.f, fmaxf(-1.f, 0.5f * detB));
    float phi = acosf(r) * (1.f/3.f);
    float c_a = __cosf(phi);
    float c_c = __cosf(phi + 2.0943951023931953f);   // + 2*pi/3
    l0 = q + 2.f*p*c_a;      // largest
    l2 = q + 2.f*p*c_c;      // smallest
    l1 = 3.f*q - l0 - l2;
  }
  float f0 = __logf(fmaxf(l0, EPSF));
  float f1 = __logf(fmaxf(l1, EPSF));
  float f2 = __logf(fmaxf(l2, EPSF));
  float d01 = l0 - l1, d12 = l1 - l2, d02 = l0 - l2;
  float mag = fmaxf(fabsf(l0), fabsf(l2));
  float thr = 1e-6f + 1e-4f * mag;
  float g01 = (d01 > thr) ? (f0 - f1) * __frcp_rn(d01)
                          : ((l0 > EPSF) ? 2.f * __frcp_rn(l0 + l1) : 0.f);
  float g12 = (d12 > thr) ? (f1 - f2) * __frcp_rn(d12)
                          : ((l1 > EPSF) ? 2.f * __frcp_rn(l1 + l2) : 0.f);
  float c2;
  if (d02 > thr) {
    c2 = (g01 - g12) * __frcp_rn(d02);
  } else {
    float m = fmaxf((l0 + l1 + l2) * (1.f/3.f), EPSF);
    c2 = (l2 > EPSF) ? -0.5f * __frcp_rn(m * m) : 0.f;
  }
  float c1 = g01 - c2 * (l0 + l1);
  float c0 = f0 - g01 * l0 + c2 * l0 * l1;
  float m2xx = Sxx*Sxx + Sxy*Sxy + Sxz*Sxz;
  float m2yy = Sxy*Sxy + Syy*Syy + Syz*Syz;
  float m2zz = Sxz*Sxz + Syz*Syz + Szz*Szz;
  float m2xy = Sxy*(Sxx + Syy) + Sxz*Syz;
  float m2xz = Sxz*(Sxx + Szz) + Sxy*Syz;
  float m2yz = Syz*(Syy + Szz) + Sxy*Sxz;
  L[0] = c0 + c1*Sxx + c2*m2xx;
  L[1] = c0 + c1*Syy + c2*m2yy;
  L[2] = c0 + c1*Szz + c2*m2zz;
  L[3] = c1*Sxy + c2*m2xy;
  L[4] = c1*Sxz + c2*m2xz;
  L[5] = c1*Syz + c2*m2yz;
}

// K7: pure logm + loss. Linear non-temporal float4 loads (read-once), no taps.
// Batch b's tensors at Sr/Sf + b*strideElems (6 fields each, stride N3).
__global__ void k7_loss(const float* __restrict__ Sr, const float* __restrict__ Sf,
                        size_t strideElems, int nb, float* __restrict__ out) {
  int t = xswz(blockIdx.x, gridDim.x) * TPB + threadIdx.x;
  float val = 0.f;
  if (t < nb * (N3 / 4)) {
    int b = t / (N3 / 4);
    int base = (t - b * (N3 / 4)) * 4;
    const float* sR = Sr + (size_t)b * strideElems;
    const float* sF = Sf + (size_t)b * strideElems;
    float4 sr[6], sf[6];
#pragma unroll
    for (int c = 0; c < 6; ++c) {
      sr[c] = nt_ld4(sR + (size_t)c * N3 + base);
      sf[c] = nt_ld4(sF + (size_t)c * N3 + base);
    }
#pragma unroll
    for (int k = 0; k < 4; ++k) {
      float s6r[6], s6f[6], Lr[6], Lf[6];
#pragma unroll
      for (int c = 0; c < 6; ++c) {
        s6r[c] = ((const float*)&sr[c])[k];
        s6f[c] = ((const float*)&sf[c])[k];
      }
      logm3(s6r, Lr);
      logm3(s6f, Lf);
      float d0 = Lr[0]-Lf[0], d1 = Lr[1]-Lf[1], d2 = Lr[2]-Lf[2];
      float d3 = Lr[3]-Lf[3], d4 = Lr[4]-Lf[4], d5 = Lr[5]-Lf[5];
      val += d0*d0 + d1*d1 + d2*d2 + 2.f*(d3*d3 + d4*d4 + d5*d5);
    }
  }
#pragma unroll
  for (int off = 32; off > 0; off >>= 1) val += __shfl_down(val, off, 64);
  __shared__ float sm[TPB / 64];
  int wave = threadIdx.x >> 6;
  if ((threadIdx.x & 63) == 0) sm[wave] = val;
  __syncthreads();
  if (threadIdx.x == 0) {
    float s = 0.f;
#pragma unroll
    for (int wv = 0; wv < TPB / 64; ++wv) s += sm[wv];
    atomicAdd(out, s * (1.0f / (float)N3));
  }
}

extern "C" void kernel_launch(void* const* d_in, const int* in_sizes, int n_in,
                              void* d_out, int out_size, void* d_ws, size_t ws_size,
                              hipStream_t stream) {
  const float* real = (const float*)d_in[0];
  const float* fake = (const float*)d_in[1];
  float* out = (float*)d_out;

  CW<7> g7, d7;
  CW<13> g13;
  {
    double g[7], sum = 0.0;
    for (int i = 0; i < 7; ++i) { double t = i - 3; g[i] = exp(-0.5 * t * t); sum += g[i]; }
    for (int i = 0; i < 7; ++i) {
      double gn = g[i] / sum;
      g7.w[i] = (float)gn;
      d7.w[i] = (float)(-(double)(i - 3) * gn);   // sigma = 1
    }
    double h[13], s2 = 0.0;
    for (int i = 0; i < 13; ++i) { double t = (i - 6) / 2.0; h[i] = exp(-0.5 * t * t); s2 += h[i]; }
    for (int i = 0; i < 13; ++i) g13.w[i] = (float)(h[i] / s2);
  }

  (void)hipMemsetAsync(d_out, 0, sizeof(float) * (size_t)out_size, stream);

  const size_t FLD = (size_t)N3;                 // one field, in floats
  float* W = (float*)d_ws;

  const size_t need_fused = 48 * FLD * sizeof(float);   // ~162 MiB
  if (ws_size >= need_fused) {
    // ---- Tier 1: all 4 volumes (r0,f0,r1,f1) in 7 dispatches ----
    float* A = W;               // 12 fields
    float* B = A + 12 * FLD;    // 12 fields
    float* C = B + 12 * FLD;    // 24 fields
    const int gV  = 4 * (N3 / 4) / TPB;          // 3456
    const int g12 = 12 * (N3 / 4) / TPB;         // 10368
    const int g24 = 24 * (N3 / 4) / TPB;         // 20736
    const int gL  = 2 * (N3 / 4) / TPB;          // 1728

    k1_dualW<<<gV,  TPB, 0, stream>>>(real, fake, real + N3, fake + N3, A, 4, g7, d7);
    k2_H    <<<gV,  TPB, 0, stream>>>(A, B, 4, g7, d7);
    k3_D    <<<g12, TPB, 0, stream>>>(B, A, 12, g7, d7);
    k4_prodW<<<gV,  TPB, 0, stream>>>(A, C, 4, g13);            // S_w -> C (24F)
    k5_blur<HW_><<<g24, TPB, 0, stream>>>(C, W, 24, g13);       // S_wd -> A|B (24F)
    k5_blur<DIM><<<g24, TPB, 0, stream>>>(W, C, 24, g13);       // S_wdh -> C (24F)
    k7_loss <<<gL,  TPB, 0, stream>>>(C, C + 6 * FLD, 12 * FLD, 2, out);
  } else {
    // ---- Fallback: per-batch, 18-field ping-pong (proven footprint) ----
    float* P0 = W;              // 6 fields
    float* P1 = P0 + 6 * FLD;   // 6 fields
    float* P2 = P1 + 6 * FLD;   // 6 fields
    const int gV  = 2 * (N3 / 4) / TPB;          // 1728
    const int g6  = 6 * (N3 / 4) / TPB;          // 5184
    const int gL  = 1 * (N3 / 4) / TPB;          // 864

    for (int b = 0; b < 2; ++b) {
      const float* rv = real + (size_t)b * N3;
      const float* fv = fake + (size_t)b * N3;
      k1_dualW<<<gV, TPB, 0, stream>>>(rv, fv, rv, fv, P0, 2, g7, d7);  // P0[0..3]
      k2_H    <<<gV, TPB, 0, stream>>>(P0, P1, 2, g7, d7);              // P1[0..5]
      k3_D    <<<g6, TPB, 0, stream>>>(P1, P0, 6, g7, d7);              // gradients
      k4_prodW<<<gV, TPB, 0, stream>>>(P0, P1, 2, g13);   // S_w: real->P1, fake->P2
      k5_blur<HW_><<<g6, TPB, 0, stream>>>(P1, P0, 6, g13);  // real S_wd -> P0
      k5_blur<HW_><<<g6, TPB, 0, stream>>>(P2, P1, 6, g13);  // fake S_wd -> P1
      k5_blur<DIM><<<g6, TPB, 0, stream>>>(P0, P2, 6, g13);  // real S_wdh -> P2
      k5_blur<DIM><<<g6, TPB, 0, stream>>>(P1, P0, 6, g13);  // fake S_wdh -> P0
      k7_loss<<<gL, TPB, 0, stream>>>(P2, P0, 0, 1, out);
    }
  }
}

// Round 16
// 319.465 us; speedup vs baseline: 1.2497x; 1.2497x over previous
//
#include <hip/hip_runtime.h>
#include <math.h>

#define DIM 96
#define HW_ 9216               // 96*96
#define N3 884736              // 96^3
#define TPB 256
#define EPSF 1e-6f

template<int K> struct CW { float w[K]; };

__device__ inline float4 ld4(const float* p) { return *reinterpret_cast<const float4*>(p); }
__device__ inline void st4(float* p, float4 v) { *reinterpret_cast<float4*>(p) = v; }
__device__ inline float4 fma4(float w, float4 a, float4 acc) {
  acc.x = fmaf(w, a.x, acc.x); acc.y = fmaf(w, a.y, acc.y);
  acc.z = fmaf(w, a.z, acc.z); acc.w = fmaf(w, a.w, acc.w); return acc;
}
// XCD-aware contiguous-chunk swizzle (grid must be divisible by 8; all ours are).
__device__ inline int xswz(int bid, int nb) { return (bid & 7) * (nb >> 3) + (bid >> 3); }

// K1: dual 7-tap conv along W over nvol volumes, 4 outputs/thread.
// Window via 3 aligned float4 loads: span [x-4, x+8), win[u] = span[u+1].
__global__ void k1_dualW(const float* __restrict__ p0, const float* __restrict__ p1,
                         const float* __restrict__ p2, const float* __restrict__ p3,
                         float* __restrict__ A, int nvol, CW<7> g, CW<7> dg) {
  int t = blockIdx.x * TPB + threadIdx.x;
  if (t >= nvol * (N3 / 4)) return;
  int base = t * 4;
  int v = base / N3, i = base - v * N3;   // i % 4 == 0
  const float* src = (v == 0) ? p0 : (v == 1) ? p1 : (v == 2) ? p2 : p3;
  int x = i % DIM;                         // multiple of 4
  float4 z = {0,0,0,0};
  float4 sp[3];
  sp[0] = (x >= 4)  ? ld4(src + i - 4) : z;
  sp[1] = ld4(src + i);
  sp[2] = (x <= 88) ? ld4(src + i + 4) : z;
  const float* spf = (const float*)sp;
  float win[10];
#pragma unroll
  for (int u = 0; u < 10; ++u) win[u] = spf[u + 1];
  float4 sa, sb;
#pragma unroll
  for (int k = 0; k < 4; ++k) {
    float a_ = 0.f, b_ = 0.f;
#pragma unroll
    for (int j = 0; j < 7; ++j) {
      float val = win[k + j];
      a_ = fmaf(g.w[j], val, a_);
      b_ = fmaf(dg.w[j], val, b_);
    }
    ((float*)&sa)[k] = a_;
    ((float*)&sb)[k] = b_;
  }
  st4(A + (size_t)(2 * v) * N3 + i, sa);
  st4(A + (size_t)(2 * v + 1) * N3 + i, sb);
}

// K2: 7-tap conv along H (float4). In fields [2v],[2v+1]. Out [3v+t]:
// t0 = Hg(Wg) [->gz], t1 = Hdg(Wg) [->gy], t2 = Hg(Wdg) [->gx]
__global__ void k2_H(const float* __restrict__ A, float* __restrict__ B,
                     int nvol, CW<7> g, CW<7> dg) {
  int t = blockIdx.x * TPB + threadIdx.x;
  if (t >= nvol * (N3 / 4)) return;
  int base = t * 4;
  int v = base / N3, i = base - v * N3;
  int h = (i / DIM) % DIM;
  const float* Wg  = A + (size_t)(2 * v) * N3;
  const float* Wdg = A + (size_t)(2 * v + 1) * N3;
  float4 t0 = {0,0,0,0}, t1 = {0,0,0,0}, t2 = {0,0,0,0};
#pragma unroll
  for (int j = -3; j <= 3; ++j) {
    int hh = h + j;
    if (0 <= hh && hh < DIM) {
      float4 a = ld4(Wg + i + j * DIM);
      t0 = fma4(g.w[j + 3], a, t0);
      t1 = fma4(dg.w[j + 3], a, t1);
      float4 b = ld4(Wdg + i + j * DIM);
      t2 = fma4(g.w[j + 3], b, t2);
    }
  }
  st4(B + (size_t)(3 * v + 0) * N3 + i, t0);
  st4(B + (size_t)(3 * v + 1) * N3 + i, t1);
  st4(B + (size_t)(3 * v + 2) * N3 + i, t2);
}

// K3: 7-tap conv along D (float4) on nf fields; field f%3==0 uses dg, else g.
__global__ void k3_D(const float* __restrict__ B, float* __restrict__ A,
                     int nf, CW<7> g, CW<7> dg) {
  int t = xswz(blockIdx.x, gridDim.x) * TPB + threadIdx.x;
  if (t >= nf * (N3 / 4)) return;
  int base = t * 4;
  int f = base / N3;
  int d = (base / HW_) % DIM;
  bool use_dg = (f % 3 == 0);
  float4 acc = {0,0,0,0};
#pragma unroll
  for (int j = -3; j <= 3; ++j) {
    int dd = d + j;
    if (0 <= dd && dd < DIM) {
      float w = use_dg ? dg.w[j + 3] : g.w[j + 3];
      acc = fma4(w, ld4(B + base + j * HW_), acc);
    }
  }
  st4(A + base, acc);
}

// K4: gradient products + 13-tap blur along W. In fields [3v+t] -> out [6v+c].
// Window via 5 aligned float4 loads/field: span [x-8, x+12), win[u]=span[u+2].
// Every loaded block is fully in-row (x%4==0); skipped blocks are all-invalid.
__global__ void k4_prodW(const float* __restrict__ A, float* __restrict__ C,
                         int nvol, CW<13> w13) {
  int t = xswz(blockIdx.x, gridDim.x) * TPB + threadIdx.x;
  if (t >= nvol * (N3 / 4)) return;
  int base = t * 4;
  int v = base / N3, i = base - v * N3;
  const float* gz = A + (size_t)(3 * v + 0) * N3;
  const float* gy = A + (size_t)(3 * v + 1) * N3;
  const float* gx = A + (size_t)(3 * v + 2) * N3;
  int x = i % DIM;
  bool c0 = (x >= 8), c1 = (x >= 4), c3 = (x <= 88), c4 = (x <= 84);
  float4 z = {0,0,0,0};
  float4 sx[5], sy[5], sz[5];
  sx[0] = c0 ? ld4(gx + i - 8) : z;
  sy[0] = c0 ? ld4(gy + i - 8) : z;
  sz[0] = c0 ? ld4(gz + i - 8) : z;
  sx[1] = c1 ? ld4(gx + i - 4) : z;
  sy[1] = c1 ? ld4(gy + i - 4) : z;
  sz[1] = c1 ? ld4(gz + i - 4) : z;
  sx[2] = ld4(gx + i);
  sy[2] = ld4(gy + i);
  sz[2] = ld4(gz + i);
  sx[3] = c3 ? ld4(gx + i + 4) : z;
  sy[3] = c3 ? ld4(gy + i + 4) : z;
  sz[3] = c3 ? ld4(gz + i + 4) : z;
  sx[4] = c4 ? ld4(gx + i + 8) : z;
  sy[4] = c4 ? ld4(gy + i + 8) : z;
  sz[4] = c4 ? ld4(gz + i + 8) : z;
  const float* fx = (const float*)sx;
  const float* fy = (const float*)sy;
  const float* fz = (const float*)sz;
  float wx[16], wy[16], wz[16];
#pragma unroll
  for (int u = 0; u < 16; ++u) {
    wx[u] = fx[u + 2];
    wy[u] = fy[u + 2];
    wz[u] = fz[u + 2];
  }
  float4 a0 = {0,0,0,0}, a1 = {0,0,0,0}, a2 = {0,0,0,0};
  float4 a3 = {0,0,0,0}, a4 = {0,0,0,0}, a5 = {0,0,0,0};
#pragma unroll
  for (int k = 0; k < 4; ++k) {
    float s0=0,s1=0,s2=0,s3=0,s4=0,s5=0;
#pragma unroll
    for (int j = 0; j < 13; ++j) {
      float w = w13.w[j];
      float a = wx[k + j], b = wy[k + j], c = wz[k + j];
      float wa = w * a, wb = w * b, wc = w * c;
      s0 = fmaf(wa, a, s0); s3 = fmaf(wa, b, s3); s4 = fmaf(wa, c, s4);
      s1 = fmaf(wb, b, s1); s5 = fmaf(wb, c, s5);
      s2 = fmaf(wc, c, s2);
    }
    ((float*)&a0)[k]=s0; ((float*)&a1)[k]=s1; ((float*)&a2)[k]=s2;
    ((float*)&a3)[k]=s3; ((float*)&a4)[k]=s4; ((float*)&a5)[k]=s5;
  }
  float* dst = C + (size_t)(6 * v) * N3;
  st4(dst + 0*N3 + i, a0); st4(dst + 1*N3 + i, a1); st4(dst + 2*N3 + i, a2);
  st4(dst + 3*N3 + i, a3); st4(dst + 4*N3 + i, a4); st4(dst + 5*N3 + i, a5);
}

// K5: 13-tap blur along axis with compile-time STRIDE (DIM=H, HW_=D) on nf
// fields (float4), In -> Out. XCD-swizzled for slab/L2 reuse.
template<int STRIDE>
__global__ void k5_blur(const float* __restrict__ In, float* __restrict__ Out,
                        int nf, CW<13> w13) {
  int t = xswz(blockIdx.x, gridDim.x) * TPB + threadIdx.x;
  if (t >= nf * (N3 / 4)) return;
  int base = t * 4;
  int c = (base / STRIDE) % DIM;
  float4 acc = {0,0,0,0};
#pragma unroll
  for (int j = -6; j <= 6; ++j) {
    int cc = c + j;
    if (0 <= cc && cc < DIM)
      acc = fma4(w13.w[j + 6], ld4(In + base + j * STRIDE), acc);
  }
  st4(Out + base, acc);
}

// ---- analytic symmetric-3x3 matrix log ----
// Trigonometric eigenvalues (descending l0>=l1>=l2) + Newton divided-difference
// polynomial interpolating y=log(max(lambda,EPS)) at x=lambda:
//   log(M) = c0 I + c1 M + c2 M^2.
__device__ inline void logm3(const float s6[6], float L[6]) {
  const float Sxx=s6[0], Syy=s6[1], Szz=s6[2], Sxy=s6[3], Sxz=s6[4], Syz=s6[5];
  float q  = (Sxx + Syy + Szz) * (1.f/3.f);
  float p1 = Sxy*Sxy + Sxz*Sxz + Syz*Syz;
  float axx = Sxx - q, ayy = Syy - q, azz = Szz - q;
  float p2 = axx*axx + ayy*ayy + azz*azz + 2.f*p1;
  float l0, l1, l2;
  if (p2 < 1e-24f) {
    l0 = l1 = l2 = q;
  } else {
    float p  = sqrtf(p2 * (1.f/6.f));
    float ip = __frcp_rn(p);
    float bxx=axx*ip, byy=ayy*ip, bzz=azz*ip;
    float bxy=Sxy*ip, bxz=Sxz*ip, byz=Syz*ip;
    float detB = bxx*(byy*bzz - byz*byz) - bxy*(bxy*bzz - byz*bxz)
               + bxz*(bxy*byz - byy*bxz);
    float r = fminf(1.f, fmaxf(-1.f, 0.5f * detB));
    float phi = acosf(r) * (1.f/3.f);
    float c_a = __cosf(phi);
    float c_c = __cosf(phi + 2.0943951023931953f);   // + 2*pi/3
    l0 = q + 2.f*p*c_a;      // largest
    l2 = q + 2.f*p*c_c;      // smallest
    l1 = 3.f*q - l0 - l2;
  }
  float f0 = __logf(fmaxf(l0, EPSF));
  float f1 = __logf(fmaxf(l1, EPSF));
  float f2 = __logf(fmaxf(l2, EPSF));
  float d01 = l0 - l1, d12 = l1 - l2, d02 = l0 - l2;
  float mag = fmaxf(fabsf(l0), fabsf(l2));
  float thr = 1e-6f + 1e-4f * mag;
  float g01 = (d01 > thr) ? (f0 - f1) * __frcp_rn(d01)
                          : ((l0 > EPSF) ? 2.f * __frcp_rn(l0 + l1) : 0.f);
  float g12 = (d12 > thr) ? (f1 - f2) * __frcp_rn(d12)
                          : ((l1 > EPSF) ? 2.f * __frcp_rn(l1 + l2) : 0.f);
  float c2;
  if (d02 > thr) {
    c2 = (g01 - g12) * __frcp_rn(d02);
  } else {
    float m = fmaxf((l0 + l1 + l2) * (1.f/3.f), EPSF);
    c2 = (l2 > EPSF) ? -0.5f * __frcp_rn(m * m) : 0.f;
  }
  float c1 = g01 - c2 * (l0 + l1);
  float c0 = f0 - g01 * l0 + c2 * l0 * l1;
  float m2xx = Sxx*Sxx + Sxy*Sxy + Sxz*Sxz;
  float m2yy = Sxy*Sxy + Syy*Syy + Syz*Syz;
  float m2zz = Sxz*Sxz + Syz*Syz + Szz*Szz;
  float m2xy = Sxy*(Sxx + Syy) + Sxz*Syz;
  float m2xz = Sxz*(Sxx + Szz) + Sxy*Syz;
  float m2yz = Syz*(Syy + Szz) + Sxy*Sxz;
  L[0] = c0 + c1*Sxx + c2*m2xx;
  L[1] = c0 + c1*Syy + c2*m2yy;
  L[2] = c0 + c1*Szz + c2*m2zz;
  L[3] = c1*Sxy + c2*m2xy;
  L[4] = c1*Sxz + c2*m2xz;
  L[5] = c1*Syz + c2*m2yz;
}

// K7: pure logm + loss. Linear float4 loads (4 voxels/thread), no taps.
// Batch b's tensors at Sr/Sf + b*strideElems (6 fields each, stride N3).
__global__ void k7_loss(const float* __restrict__ Sr, const float* __restrict__ Sf,
                        size_t strideElems, int nb, float* __restrict__ out) {
  int t = xswz(blockIdx.x, gridDim.x) * TPB + threadIdx.x;
  float val = 0.f;
  if (t < nb * (N3 / 4)) {
    int b = t / (N3 / 4);
    int base = (t - b * (N3 / 4)) * 4;
    const float* sR = Sr + (size_t)b * strideElems;
    const float* sF = Sf + (size_t)b * strideElems;
    float4 sr[6], sf[6];
#pragma unroll
    for (int c = 0; c < 6; ++c) {
      sr[c] = ld4(sR + (size_t)c * N3 + base);
      sf[c] = ld4(sF + (size_t)c * N3 + base);
    }
#pragma unroll
    for (int k = 0; k < 4; ++k) {
      float s6r[6], s6f[6], Lr[6], Lf[6];
#pragma unroll
      for (int c = 0; c < 6; ++c) {
        s6r[c] = ((const float*)&sr[c])[k];
        s6f[c] = ((const float*)&sf[c])[k];
      }
      logm3(s6r, Lr);
      logm3(s6f, Lf);
      float d0 = Lr[0]-Lf[0], d1 = Lr[1]-Lf[1], d2 = Lr[2]-Lf[2];
      float d3 = Lr[3]-Lf[3], d4 = Lr[4]-Lf[4], d5 = Lr[5]-Lf[5];
      val += d0*d0 + d1*d1 + d2*d2 + 2.f*(d3*d3 + d4*d4 + d5*d5);
    }
  }
#pragma unroll
  for (int off = 32; off > 0; off >>= 1) val += __shfl_down(val, off, 64);
  __shared__ float sm[TPB / 64];
  int wave = threadIdx.x >> 6;
  if ((threadIdx.x & 63) == 0) sm[wave] = val;
  __syncthreads();
  if (threadIdx.x == 0) {
    float s = 0.f;
#pragma unroll
    for (int wv = 0; wv < TPB / 64; ++wv) s += sm[wv];
    atomicAdd(out, s * (1.0f / (float)N3));
  }
}

extern "C" void kernel_launch(void* const* d_in, const int* in_sizes, int n_in,
                              void* d_out, int out_size, void* d_ws, size_t ws_size,
                              hipStream_t stream) {
  const float* real = (const float*)d_in[0];
  const float* fake = (const float*)d_in[1];
  float* out = (float*)d_out;

  CW<7> g7, d7;
  CW<13> g13;
  {
    double g[7], sum = 0.0;
    for (int i = 0; i < 7; ++i) { double t = i - 3; g[i] = exp(-0.5 * t * t); sum += g[i]; }
    for (int i = 0; i < 7; ++i) {
      double gn = g[i] / sum;
      g7.w[i] = (float)gn;
      d7.w[i] = (float)(-(double)(i - 3) * gn);   // sigma = 1
    }
    double h[13], s2 = 0.0;
    for (int i = 0; i < 13; ++i) { double t = (i - 6) / 2.0; h[i] = exp(-0.5 * t * t); s2 += h[i]; }
    for (int i = 0; i < 13; ++i) g13.w[i] = (float)(h[i] / s2);
  }

  (void)hipMemsetAsync(d_out, 0, sizeof(float) * (size_t)out_size, stream);

  const size_t FLD = (size_t)N3;                 // one field, in floats
  float* W = (float*)d_ws;

  const size_t need_fused = 48 * FLD * sizeof(float);   // ~162 MiB
  if (ws_size >= need_fused) {
    // ---- Tier 1: all 4 volumes (r0,f0,r1,f1) in 7 dispatches ----
    float* A = W;               // 12 fields
    float* B = A + 12 * FLD;    // 12 fields
    float* C = B + 12 * FLD;    // 24 fields
    const int gV  = 4 * (N3 / 4) / TPB;          // 3456
    const int g12 = 12 * (N3 / 4) / TPB;         // 10368
    const int g24 = 24 * (N3 / 4) / TPB;         // 20736
    const int gL  = 2 * (N3 / 4) / TPB;          // 1728

    k1_dualW<<<gV,  TPB, 0, stream>>>(real, fake, real + N3, fake + N3, A, 4, g7, d7);
    k2_H    <<<gV,  TPB, 0, stream>>>(A, B, 4, g7, d7);
    k3_D    <<<g12, TPB, 0, stream>>>(B, A, 12, g7, d7);
    k4_prodW<<<gV,  TPB, 0, stream>>>(A, C, 4, g13);            // S_w -> C (24F)
    k5_blur<HW_><<<g24, TPB, 0, stream>>>(C, W, 24, g13);       // S_wd -> A|B (24F)
    k5_blur<DIM><<<g24, TPB, 0, stream>>>(W, C, 24, g13);       // S_wdh -> C (24F)
    k7_loss <<<gL,  TPB, 0, stream>>>(C, C + 6 * FLD, 12 * FLD, 2, out);
  } else {
    // ---- Fallback: per-batch, 18-field ping-pong (proven footprint) ----
    float* P0 = W;              // 6 fields
    float* P1 = P0 + 6 * FLD;   // 6 fields
    float* P2 = P1 + 6 * FLD;   // 6 fields
    const int gV  = 2 * (N3 / 4) / TPB;          // 1728
    const int g6  = 6 * (N3 / 4) / TPB;          // 5184
    const int gL  = 1 * (N3 / 4) / TPB;          // 864

    for (int b = 0; b < 2; ++b) {
      const float* rv = real + (size_t)b * N3;
      const float* fv = fake + (size_t)b * N3;
      k1_dualW<<<gV, TPB, 0, stream>>>(rv, fv, rv, fv, P0, 2, g7, d7);  // P0[0..3]
      k2_H    <<<gV, TPB, 0, stream>>>(P0, P1, 2, g7, d7);              // P1[0..5]
      k3_D    <<<g6, TPB, 0, stream>>>(P1, P0, 6, g7, d7);              // gradients
      k4_prodW<<<gV, TPB, 0, stream>>>(P0, P1, 2, g13);   // S_w: real->P1, fake->P2
      k5_blur<HW_><<<g6, TPB, 0, stream>>>(P1, P0, 6, g13);  // real S_wd -> P0
      k5_blur<HW_><<<g6, TPB, 0, stream>>>(P2, P1, 6, g13);  // fake S_wd -> P1
      k5_blur<DIM><<<g6, TPB, 0, stream>>>(P0, P2, 6, g13);  // real S_wdh -> P2
      k5_blur<DIM><<<g6, TPB, 0, stream>>>(P1, P0, 6, g13);  // fake S_wdh -> P0
      k7_loss<<<gL, TPB, 0, stream>>>(P2, P0, 0, 1, out);
    }
  }
}